// Round 5
// baseline (215.742 us; speedup 1.0000x reference)
//
#include <hip/hip_runtime.h>
#include <hip/hip_bf16.h>
#include <cstdint>
#include <cstddef>

#define N_ROWS 8192
#define DIM    512
#define C_EXPSCALE 14.4269504088896340736f   // 10*log2(e); exp(sim-10)=exp2((cos-1)*this)

typedef __attribute__((ext_vector_type(8))) short bf16x8;
typedef __attribute__((ext_vector_type(4))) float f32x4;

__device__ __forceinline__ ushort f2bf(float x) {
  union { float f; uint32_t u; } c; c.f = x;
  uint32_t r = (c.u + 0x7fffu + ((c.u >> 16) & 1u)) >> 16;
  return (ushort)r;
}

// ---------------- prep: fp32 row norms, fp32 diag, bf16 normalized copies ----
__global__ __launch_bounds__(256) void prep_kernel(const float* __restrict__ V,
                                                   const float* __restrict__ U,
                                                   ushort* __restrict__ Vn,
                                                   ushort* __restrict__ Un,
                                                   float* __restrict__ diag,
                                                   float* __restrict__ row_sum,
                                                   float* __restrict__ col_sum) {
  const int row = blockIdx.x * 4 + (threadIdx.x >> 6);
  const int l = threadIdx.x & 63;
  const float4* v4 = (const float4*)(V + (size_t)row * DIM) + l * 2;
  const float4* u4 = (const float4*)(U + (size_t)row * DIM) + l * 2;
  float4 a0 = v4[0], a1 = v4[1];
  float4 b0 = u4[0], b1 = u4[1];
  float sv = a0.x*a0.x + a0.y*a0.y + a0.z*a0.z + a0.w*a0.w
           + a1.x*a1.x + a1.y*a1.y + a1.z*a1.z + a1.w*a1.w;
  float su = b0.x*b0.x + b0.y*b0.y + b0.z*b0.z + b0.w*b0.w
           + b1.x*b1.x + b1.y*b1.y + b1.z*b1.z + b1.w*b1.w;
  float sd = a0.x*b0.x + a0.y*b0.y + a0.z*b0.z + a0.w*b0.w
           + a1.x*b1.x + a1.y*b1.y + a1.z*b1.z + a1.w*b1.w;
#pragma unroll
  for (int m = 1; m < 64; m <<= 1) {
    sv += __shfl_xor(sv, m, 64);
    su += __shfl_xor(su, m, 64);
    sd += __shfl_xor(sd, m, 64);
  }
  const float rv = 1.0f / fmaxf(sqrtf(sv), 1e-8f);
  const float ru = 1.0f / fmaxf(sqrtf(su), 1e-8f);
  if (l == 0) {
    diag[row] = sd * rv * ru * 10.0f;
    row_sum[row] = 0.0f;
    col_sum[row] = 0.0f;
  }

  const float av[8] = {a0.x, a0.y, a0.z, a0.w, a1.x, a1.y, a1.z, a1.w};
  const float bv[8] = {b0.x, b0.y, b0.z, b0.w, b1.x, b1.y, b1.z, b1.w};
  union { ushort us[8]; uint4 q; } pv, pu;
#pragma unroll
  for (int j = 0; j < 8; ++j) {
    pv.us[j] = f2bf(av[j] * rv);
    pu.us[j] = f2bf(bv[j] * ru);
  }
  *(uint4*)(Vn + (size_t)row * DIM + l * 8) = pv.q;
  *(uint4*)(Un + (size_t)row * DIM + l * 8) = pu.q;
}

// ---- 256x256 GEMM (bf16 MFMA) + exp(sim-10) + row/col sums ----
// DIRECT-FROM-L2 fragments, ZERO main-loop barriers. Each lane loads its MFMA
// fragment straight from Vn/Un as a 16B global_load_dwordx4:
//   A frag (m,h): Vn[br + wm*128 + m*16 + l15][h*32 + lhi*8 .. +8]
//   B frag (n,h): Un[bc + wn*64  + n*16 + l15][h*32 + lhi*8 .. +8]
// A wave's 64 lanes = 16 rows x 64 contiguous bytes; consecutive h touch the
// other 64B of each 128B line (full line use). No LDS staging -> no barriers
// -> waves on a SIMD drift out of phase; one wave's loads overlap the other's
// MFMAs (m114). Register double-buffer over 16 half-tiles (K=32 each, two
// named sets A0/B0,A1/B1 -- static indexing): 32 MFMAs per half, 12 loads of
// half h+1 in flight under them (compiler-counted vmcnt).
// L2 redundancy: A 4x, B 2x per block = 192KB/K-tile; panels L2-resident via
// the XCD map. Accumulation order per acc element: K = 0,32,...,480 --
// identical sequence to all prior rounds (bit-exact).
__global__ __launch_bounds__(512, 2) void gemm_lse_kernel(const ushort* __restrict__ Vn,
                                                          const ushort* __restrict__ Un,
                                                          float* __restrict__ row_sum,
                                                          float* __restrict__ col_sum) {
  __shared__ float Red[1536];   // 6 KiB, epilogue reductions only

  const int tid  = threadIdx.x;
  const int lane = tid & 63;
  const int wid  = tid >> 6;
  const int wm   = wid >> 2;       // 0..1
  const int wn   = wid & 3;        // 0..3
  const int l15  = lane & 15;
  const int lhi  = lane >> 4;      // 0..3

  // XCD map: 8 XCDs tile the 32x32 grid as 4x2 supergrid of 8x16 each
  const int bid  = blockIdx.x;
  const int xcd  = bid & 7;
  const int x    = bid >> 3;
  const int rt   = (xcd >> 1) * 8 + (x >> 4);
  const int ct   = (xcd & 1) * 16 + (x & 15);
  const int br   = rt << 8;
  const int bc   = ct << 8;

  // per-lane fragment base pointers (per m / per n; h*64B folds into imm offset)
  const ushort* aRow = Vn + (size_t)(br + wm * 128 + l15) * DIM + lhi * 8;
  const ushort* bRow = Un + (size_t)(bc + wn * 64 + l15) * DIM + lhi * 8;
  const ushort* aF[8]; const ushort* bF[4];
#pragma unroll
  for (int m = 0; m < 8; ++m) aF[m] = aRow + m * 16 * DIM;
#pragma unroll
  for (int n = 0; n < 4; ++n) bF[n] = bRow + n * 16 * DIM;

  f32x4 acc[8][4];
#pragma unroll
  for (int m = 0; m < 8; ++m)
#pragma unroll
    for (int n = 0; n < 4; ++n) acc[m][n] = (f32x4){0.f, 0.f, 0.f, 0.f};

  bf16x8 A0[8], B0[4], A1[8], B1[4];

  // prologue: half-tile 0 into set0
#pragma unroll
  for (int m = 0; m < 8; ++m) A0[m] = *(const bf16x8*)(aF[m]);
#pragma unroll
  for (int n = 0; n < 4; ++n) B0[n] = *(const bf16x8*)(bF[n]);

#pragma unroll
  for (int h = 0; h < 16; h += 2) {
    // prefetch half h+1 into set1 (overlaps set0's MFMAs via counted vmcnt)
#pragma unroll
    for (int m = 0; m < 8; ++m) A1[m] = *(const bf16x8*)(aF[m] + (h + 1) * 32);
#pragma unroll
    for (int n = 0; n < 4; ++n) B1[n] = *(const bf16x8*)(bF[n] + (h + 1) * 32);

    __builtin_amdgcn_s_setprio(1);
#pragma unroll
    for (int m = 0; m < 8; ++m)
#pragma unroll
      for (int n = 0; n < 4; ++n)
        acc[m][n] = __builtin_amdgcn_mfma_f32_16x16x32_bf16(A0[m], B0[n], acc[m][n], 0, 0, 0);
    __builtin_amdgcn_s_setprio(0);

    // prefetch half h+2 into set0
    if (h + 2 < 16) {
#pragma unroll
      for (int m = 0; m < 8; ++m) A0[m] = *(const bf16x8*)(aF[m] + (h + 2) * 32);
#pragma unroll
      for (int n = 0; n < 4; ++n) B0[n] = *(const bf16x8*)(bF[n] + (h + 2) * 32);
    }

    __builtin_amdgcn_s_setprio(1);
#pragma unroll
    for (int m = 0; m < 8; ++m)
#pragma unroll
      for (int n = 0; n < 4; ++n)
        acc[m][n] = __builtin_amdgcn_mfma_f32_16x16x32_bf16(A1[m], B1[n], acc[m][n], 0, 0, 0);
    __builtin_amdgcn_s_setprio(0);
  }

  // ---- epilogue: exp(sim-10), row/col partial sums ----
  float* red_row = Red;            // [4][256] floats (by wn)
  float* red_col = Red + 1024;     // [2][256] floats (by wm)

#pragma unroll
  for (int m = 0; m < 8; ++m)
#pragma unroll
    for (int n = 0; n < 4; ++n) {
      f32x4 v = acc[m][n];
#pragma unroll
      for (int r = 0; r < 4; ++r) v[r] = __builtin_amdgcn_exp2f((v[r] - 1.0f) * C_EXPSCALE);
      acc[m][n] = v;
    }

#pragma unroll
  for (int m = 0; m < 8; ++m)
#pragma unroll
    for (int r = 0; r < 4; ++r) {
      float s = acc[m][0][r] + acc[m][1][r] + acc[m][2][r] + acc[m][3][r];
      s += __shfl_xor(s, 1, 64);
      s += __shfl_xor(s, 2, 64);
      s += __shfl_xor(s, 4, 64);
      s += __shfl_xor(s, 8, 64);
      if (l15 == 0) red_row[wn * 256 + wm * 128 + m * 16 + lhi * 4 + r] = s;
    }
#pragma unroll
  for (int n = 0; n < 4; ++n) {
    float s = 0.f;
#pragma unroll
    for (int m = 0; m < 8; ++m)
      s += acc[m][n][0] + acc[m][n][1] + acc[m][n][2] + acc[m][n][3];
    s += __shfl_xor(s, 16, 64);
    s += __shfl_xor(s, 32, 64);
    if (lane < 16) red_col[wm * 256 + wn * 64 + n * 16 + lane] = s;
  }
  __syncthreads();

  if (tid < 256) {
    float s = red_row[tid] + red_row[256 + tid] + red_row[512 + tid] + red_row[768 + tid];
    atomicAdd(&row_sum[br + tid], s);
  } else {
    const int c = tid - 256;
    float s = red_col[c] + red_col[256 + c];
    atomicAdd(&col_sum[bc + c], s);
  }
}

// ---------------- finalize ----------------
__global__ __launch_bounds__(1024) void finalize_kernel(const float* __restrict__ row_sum,
                                                        const float* __restrict__ col_sum,
                                                        const float* __restrict__ diag,
                                                        float* __restrict__ out) {
  __shared__ float sred[1024];
  float acc = 0.0f;
  for (int i = threadIdx.x; i < N_ROWS; i += 1024) {
    const float lse_r = 10.0f + logf(row_sum[i]);
    const float lse_c = 10.0f + logf(col_sum[i]);
    acc += 0.75f * lse_r + 0.25f * lse_c - diag[i];
  }
  sred[threadIdx.x] = acc;
  __syncthreads();
  for (int s = 512; s > 0; s >>= 1) {
    if ((int)threadIdx.x < s) sred[threadIdx.x] += sred[threadIdx.x + s];
    __syncthreads();
  }
  if (threadIdx.x == 0) out[0] = sred[0] / (float)N_ROWS;
}

extern "C" void kernel_launch(void* const* d_in, const int* in_sizes, int n_in,
                              void* d_out, int out_size, void* d_ws, size_t ws_size,
                              hipStream_t stream) {
  const float* V = (const float*)d_in[0];
  const float* U = (const float*)d_in[1];
  float* out = (float*)d_out;

  char* ws = (char*)d_ws;
  ushort* Vn      = (ushort*)(ws);
  ushort* Un      = (ushort*)(ws + 8388608);
  float*  diag    = (float*)(ws + 16777216);
  float*  row_sum = (float*)(ws + 16777216 + 32768);
  float*  col_sum = (float*)(ws + 16777216 + 65536);

  prep_kernel<<<N_ROWS / 4, 256, 0, stream>>>(V, U, Vn, Un, diag, row_sum, col_sum);
  gemm_lse_kernel<<<(N_ROWS / 256) * (N_ROWS / 256), 512, 0, stream>>>(Vn, Un, row_sum, col_sum);
  finalize_kernel<<<1, 1024, 0, stream>>>(row_sum, col_sum, diag, out);
}

// Round 6
// 97.439 us; speedup vs baseline: 2.2141x; 2.2141x over previous
//
#include <hip/hip_runtime.h>
#include <hip/hip_bf16.h>
#include <cstdint>
#include <cstddef>

#define N_ROWS 8192
#define DIM    512
#define NKT    8          // K-tiles of 64
#define C_EXPSCALE 14.4269504088896340736f   // 10*log2(e); exp(sim-10)=exp2((cos-1)*this)

typedef __attribute__((ext_vector_type(8))) short bf16x8;
typedef __attribute__((ext_vector_type(4))) float f32x4;

__device__ __forceinline__ ushort f2bf(float x) {
  union { float f; uint32_t u; } c; c.f = x;
  uint32_t r = (c.u + 0x7fffu + ((c.u >> 16) & 1u)) >> 16;
  return (ushort)r;
}

// ---------------- prep: fp32 row norms, fp32 diag, bf16 normalized copies ----
__global__ __launch_bounds__(256) void prep_kernel(const float* __restrict__ V,
                                                   const float* __restrict__ U,
                                                   ushort* __restrict__ Vn,
                                                   ushort* __restrict__ Un,
                                                   float* __restrict__ diag,
                                                   float* __restrict__ row_sum,
                                                   float* __restrict__ col_sum) {
  const int row = blockIdx.x * 4 + (threadIdx.x >> 6);
  const int l = threadIdx.x & 63;
  const float4* v4 = (const float4*)(V + (size_t)row * DIM) + l * 2;
  const float4* u4 = (const float4*)(U + (size_t)row * DIM) + l * 2;
  float4 a0 = v4[0], a1 = v4[1];
  float4 b0 = u4[0], b1 = u4[1];
  float sv = a0.x*a0.x + a0.y*a0.y + a0.z*a0.z + a0.w*a0.w
           + a1.x*a1.x + a1.y*a1.y + a1.z*a1.z + a1.w*a1.w;
  float su = b0.x*b0.x + b0.y*b0.y + b0.z*b0.z + b0.w*b0.w
           + b1.x*b1.x + b1.y*b1.y + b1.z*b1.z + b1.w*b1.w;
  float sd = a0.x*b0.x + a0.y*b0.y + a0.z*b0.z + a0.w*b0.w
           + a1.x*b1.x + a1.y*b1.y + a1.z*b1.z + a1.w*b1.w;
#pragma unroll
  for (int m = 1; m < 64; m <<= 1) {
    sv += __shfl_xor(sv, m, 64);
    su += __shfl_xor(su, m, 64);
    sd += __shfl_xor(sd, m, 64);
  }
  const float rv = 1.0f / fmaxf(sqrtf(sv), 1e-8f);
  const float ru = 1.0f / fmaxf(sqrtf(su), 1e-8f);
  if (l == 0) {
    diag[row] = sd * rv * ru * 10.0f;
    row_sum[row] = 0.0f;
    col_sum[row] = 0.0f;
  }

  const float av[8] = {a0.x, a0.y, a0.z, a0.w, a1.x, a1.y, a1.z, a1.w};
  const float bv[8] = {b0.x, b0.y, b0.z, b0.w, b1.x, b1.y, b1.z, b1.w};
  union { ushort us[8]; uint4 q; } pv, pu;
#pragma unroll
  for (int j = 0; j < 8; ++j) {
    pv.us[j] = f2bf(av[j] * rv);
    pu.us[j] = f2bf(bv[j] * ru);
  }
  *(uint4*)(Vn + (size_t)row * DIM + l * 8) = pv.q;
  *(uint4*)(Un + (size_t)row * DIM + l * 8) = pu.q;
}

// ---- 256x256 GEMM (bf16 MFMA) + exp(sim-10) + row/col sums ----
// R4 unpinned loop + L2-RESIDENCY XCD MAP.
// Map: xcd = bid&7 owns a fixed 4-ct column stripe (B = 4 x 256KB = 1 MB,
// L2-resident across ALL rounds); rt streams in windows of 8 per round
// (A = 2 MB/round, reused x4 within the round). Round working set = 3 MB
// < 4 MB L2 (old map: 2rt x 16ct = 4.5 MB > 4 MB -> B re-fetched from L3
// every round; that L3 loop was the ~6 TB/s operand-supply ceiling all
// five prior variants hit).
// vmcnt ledger: invariant 8 outstanding (tile j+1) at tile top; stage adds 8
// -> vmcnt(8) completes tile j+1 exactly; j=6 drains vmcnt(0) for tile 7.
// Accumulation order per acc element identical to prior rounds (bit-exact).
#define AREG(s,h) ((s)*32768 + (h)*16384)
#define BREG(s,h) (65536 + (s)*32768 + (h)*16384)

__global__ __launch_bounds__(512, 2) void gemm_lse_kernel(const ushort* __restrict__ Vn,
                                                          const ushort* __restrict__ Un,
                                                          float* __restrict__ row_sum,
                                                          float* __restrict__ col_sum) {
  __shared__ ushort Tile[65536];   // 128 KiB

  const int tid  = threadIdx.x;
  const int lane = tid & 63;
  const int wid  = tid >> 6;
  const int wm   = wid >> 2;       // 0..1
  const int wn   = wid & 3;        // 0..3
  const int l15  = lane & 15;
  const int lhi  = lane >> 4;      // 0..3
  const int sw7  = l15 & 7;

  // L2-residency map: per XCD, B stripe fixed (1 MB resident), A streams.
  const int bid  = blockIdx.x;
  const int xcd  = bid & 7;
  const int x    = bid >> 3;               // 0..127
  const int rt   = x >> 2;                 // 0..31 (8 per round window)
  const int ct   = xcd * 4 + (x & 3);      // fixed 4-col stripe per XCD
  const int br   = rt << 8;
  const int bc   = ct << 8;

  // ---- hoisted per-lane global staging bases (8 x 64-bit) ----
  const int r0 = tid >> 3,          seg0 = (tid & 7) ^ (r0 & 7);
  const int r1 = (512 + tid) >> 3,  seg1 = ((512 + tid) & 7) ^ (r1 & 7);
  const ushort* gA0_0 = Vn + (size_t)(br + r0) * DIM + seg0 * 8;
  const ushort* gA0_1 = Vn + (size_t)(br + r1) * DIM + seg1 * 8;
  const ushort* gA1_0 = Vn + (size_t)(br + 128 + r0) * DIM + seg0 * 8;
  const ushort* gA1_1 = Vn + (size_t)(br + 128 + r1) * DIM + seg1 * 8;
  const ushort* gB0_0 = Un + (size_t)(bc + r0) * DIM + seg0 * 8;
  const ushort* gB0_1 = Un + (size_t)(bc + r1) * DIM + seg1 * 8;
  const ushort* gB1_0 = Un + (size_t)(bc + 128 + r0) * DIM + seg0 * 8;
  const ushort* gB1_1 = Un + (size_t)(bc + 128 + r1) * DIM + seg1 * 8;

  auto stg = [&](const ushort* g0, const ushort* g1, int kt, int region) {
    __builtin_amdgcn_global_load_lds(
        (const __attribute__((address_space(1))) unsigned int*)(g0 + kt * 64),
        (__attribute__((address_space(3))) unsigned int*)((char*)Tile + region + wid * 1024),
        16, 0, 0);
    __builtin_amdgcn_global_load_lds(
        (const __attribute__((address_space(1))) unsigned int*)(g1 + kt * 64),
        (__attribute__((address_space(3))) unsigned int*)((char*)Tile + region + 8192 + wid * 1024),
        16, 0, 0);
  };
  auto stgA = [&](int buf, int half, int kt) {
    stg(half ? gA1_0 : gA0_0, half ? gA1_1 : gA0_1, kt, AREG(buf, half));
  };
  auto stgB = [&](int buf, int half, int kt) {
    stg(half ? gB1_0 : gB0_0, half ? gB1_1 : gB0_1, kt, BREG(buf, half));
  };

  // ---- hoisted LDS read bases (8 x 32-bit); slot(kk=1) = slot(kk=0)^4 ----
  const char* TB = (const char*)Tile;
  const int aoff = wm * 16384 + l15 * 128;
  const int boff = (wn >> 1) * 16384 + ((wn & 1) * 64 + l15) * 128;
  const int sl0  = ((0 | lhi) ^ sw7) * 16;
  const int sl1  = ((4 | lhi) ^ sw7) * 16;
  const char* pA[2][2] = { { TB + aoff + sl0,          TB + aoff + sl1 },
                           { TB + 32768 + aoff + sl0,  TB + 32768 + aoff + sl1 } };
  const char* pB[2][2] = { { TB + 65536 + boff + sl0,  TB + 65536 + boff + sl1 },
                           { TB + 98304 + boff + sl0,  TB + 98304 + boff + sl1 } };

  f32x4 acc[8][4];
#pragma unroll
  for (int m = 0; m < 8; ++m)
#pragma unroll
    for (int n = 0; n < 4; ++n) acc[m][n] = (f32x4){0.f, 0.f, 0.f, 0.f};

  // prologue: tile0 complete (8 loads) + tile1 (8 loads) in flight
  stgA(0, 0, 0); stgA(0, 1, 0); stgB(0, 0, 0); stgB(0, 1, 0);
  stgA(1, 0, 1); stgA(1, 1, 1); stgB(1, 0, 1); stgB(1, 1, 1);
  asm volatile("s_waitcnt vmcnt(8)" ::: "memory");   // tile0 landed; tile1 in flight
  __builtin_amdgcn_s_barrier();
  asm volatile("" ::: "memory");

#pragma unroll
  for (int j = 0; j < NKT; ++j) {
    const int b = j & 1;

    bf16x8 Af[8][2], Bf[4][2];
    // issue all B reads + first half of A reads (compiler interleaves/counts)
#pragma unroll
    for (int n = 0; n < 4; ++n) {
      Bf[n][0] = *(const bf16x8*)(pB[b][0] + n * 2048);
      Bf[n][1] = *(const bf16x8*)(pB[b][1] + n * 2048);
    }
#pragma unroll
    for (int m = 0; m < 4; ++m) {
      Af[m][0] = *(const bf16x8*)(pA[b][0] + m * 2048);
      Af[m][1] = *(const bf16x8*)(pA[b][1] + m * 2048);
    }

    // quad 0 (m0-1 x n0-3) -- no pins; compiler inserts counted lgkm waits
    __builtin_amdgcn_s_setprio(1);
#pragma unroll
    for (int m = 0; m < 2; ++m)
#pragma unroll
      for (int n = 0; n < 4; ++n) {
        acc[m][n] = __builtin_amdgcn_mfma_f32_16x16x32_bf16(Af[m][0], Bf[n][0], acc[m][n], 0, 0, 0);
        acc[m][n] = __builtin_amdgcn_mfma_f32_16x16x32_bf16(Af[m][1], Bf[n][1], acc[m][n], 0, 0, 0);
      }
    __builtin_amdgcn_s_setprio(0);

    // issue remaining A reads
#pragma unroll
    for (int m = 4; m < 8; ++m) {
      Af[m][0] = *(const bf16x8*)(pA[b][0] + m * 2048);
      Af[m][1] = *(const bf16x8*)(pA[b][1] + m * 2048);
    }

    // quads 1-2 (m2-5 x n0-3)
    __builtin_amdgcn_s_setprio(1);
#pragma unroll
    for (int m = 2; m < 6; ++m)
#pragma unroll
      for (int n = 0; n < 4; ++n) {
        acc[m][n] = __builtin_amdgcn_mfma_f32_16x16x32_bf16(Af[m][0], Bf[n][0], acc[m][n], 0, 0, 0);
        acc[m][n] = __builtin_amdgcn_mfma_f32_16x16x32_bf16(Af[m][1], Bf[n][1], acc[m][n], 0, 0, 0);
      }
    __builtin_amdgcn_s_setprio(0);

    // WAR fence + stage tile j+2 over buf b (reads of buf b must be COMPLETE)
    if (j + 2 < NKT) {
      asm volatile("s_waitcnt lgkmcnt(0)" ::: "memory");
      __builtin_amdgcn_s_barrier();
      asm volatile("" ::: "memory");
      stgA(b, 0, j + 2); stgA(b, 1, j + 2);
      stgB(b, 0, j + 2); stgB(b, 1, j + 2);
    }

    // quad 3 (m6-7 x n0-3) -- frags already in regs; overlaps stage issue
    __builtin_amdgcn_s_setprio(1);
#pragma unroll
    for (int m = 6; m < 8; ++m)
#pragma unroll
      for (int n = 0; n < 4; ++n) {
        acc[m][n] = __builtin_amdgcn_mfma_f32_16x16x32_bf16(Af[m][0], Bf[n][0], acc[m][n], 0, 0, 0);
        acc[m][n] = __builtin_amdgcn_mfma_f32_16x16x32_bf16(Af[m][1], Bf[n][1], acc[m][n], 0, 0, 0);
      }
    __builtin_amdgcn_s_setprio(0);

    // drain: tile j+1 complete before its reads at j+1
    if (j < NKT - 1) {
      if (j < NKT - 2) {
        asm volatile("s_waitcnt vmcnt(8)" ::: "memory");
      } else {
        asm volatile("s_waitcnt vmcnt(0)" ::: "memory");
      }
      __builtin_amdgcn_s_barrier();
      asm volatile("" ::: "memory");
    }
  }

  // ---- epilogue: exp(sim-10), row/col partial sums (reuse tile LDS) ----
  // (last tile = buf1; red arrays live in buf0's bytes 0-2047 -> no overlap)
  float* red_row = (float*)Tile;           // [4][256] floats (by wn)
  float* red_col = (float*)Tile + 1024;    // [2][256] floats (by wm)

#pragma unroll
  for (int m = 0; m < 8; ++m)
#pragma unroll
    for (int n = 0; n < 4; ++n) {
      f32x4 v = acc[m][n];
#pragma unroll
      for (int r = 0; r < 4; ++r) v[r] = __builtin_amdgcn_exp2f((v[r] - 1.0f) * C_EXPSCALE);
      acc[m][n] = v;
    }

#pragma unroll
  for (int m = 0; m < 8; ++m)
#pragma unroll
    for (int r = 0; r < 4; ++r) {
      float s = acc[m][0][r] + acc[m][1][r] + acc[m][2][r] + acc[m][3][r];
      s += __shfl_xor(s, 1, 64);
      s += __shfl_xor(s, 2, 64);
      s += __shfl_xor(s, 4, 64);
      s += __shfl_xor(s, 8, 64);
      if (l15 == 0) red_row[wn * 256 + wm * 128 + m * 16 + lhi * 4 + r] = s;
    }
#pragma unroll
  for (int n = 0; n < 4; ++n) {
    float s = 0.f;
#pragma unroll
    for (int m = 0; m < 8; ++m)
      s += acc[m][n][0] + acc[m][n][1] + acc[m][n][2] + acc[m][n][3];
    s += __shfl_xor(s, 16, 64);
    s += __shfl_xor(s, 32, 64);
    if (lane < 16) red_col[wm * 256 + wn * 64 + n * 16 + lane] = s;
  }
  __syncthreads();

  if (tid < 256) {
    float s = red_row[tid] + red_row[256 + tid] + red_row[512 + tid] + red_row[768 + tid];
    atomicAdd(&row_sum[br + tid], s);
  } else {
    const int c = tid - 256;
    float s = red_col[c] + red_col[256 + c];
    atomicAdd(&col_sum[bc + c], s);
  }
}

// ---------------- finalize ----------------
__global__ __launch_bounds__(1024) void finalize_kernel(const float* __restrict__ row_sum,
                                                        const float* __restrict__ col_sum,
                                                        const float* __restrict__ diag,
                                                        float* __restrict__ out) {
  __shared__ float sred[1024];
  float acc = 0.0f;
  for (int i = threadIdx.x; i < N_ROWS; i += 1024) {
    const float lse_r = 10.0f + logf(row_sum[i]);
    const float lse_c = 10.0f + logf(col_sum[i]);
    acc += 0.75f * lse_r + 0.25f * lse_c - diag[i];
  }
  sred[threadIdx.x] = acc;
  __syncthreads();
  for (int s = 512; s > 0; s >>= 1) {
    if ((int)threadIdx.x < s) sred[threadIdx.x] += sred[threadIdx.x + s];
    __syncthreads();
  }
  if (threadIdx.x == 0) out[0] = sred[0] / (float)N_ROWS;
}

extern "C" void kernel_launch(void* const* d_in, const int* in_sizes, int n_in,
                              void* d_out, int out_size, void* d_ws, size_t ws_size,
                              hipStream_t stream) {
  const float* V = (const float*)d_in[0];
  const float* U = (const float*)d_in[1];
  float* out = (float*)d_out;

  char* ws = (char*)d_ws;
  ushort* Vn      = (ushort*)(ws);
  ushort* Un      = (ushort*)(ws + 8388608);
  float*  diag    = (float*)(ws + 16777216);
  float*  row_sum = (float*)(ws + 16777216 + 32768);
  float*  col_sum = (float*)(ws + 16777216 + 65536);

  prep_kernel<<<N_ROWS / 4, 256, 0, stream>>>(V, U, Vn, Un, diag, row_sum, col_sum);
  gemm_lse_kernel<<<(N_ROWS / 256) * (N_ROWS / 256), 512, 0, stream>>>(Vn, Un, row_sum, col_sum);
  finalize_kernel<<<1, 1024, 0, stream>>>(row_sum, col_sum, diag, out);
}